// Round 3
// baseline (1867.587 us; speedup 1.0000x reference)
//
#include <hip/hip_runtime.h>
#include <hip/hip_bf16.h>

// Problem constants
#define BQ   16
#define CCH  256
#define C2   512
#define NHH  4
#define HD   64
#define HWP  4096   // H*W = 64*64

typedef unsigned short u16;
typedef unsigned int   u32;

__device__ __forceinline__ float bf2f(u16 h) {
    union { u32 u; float f; } v; v.u = (u32)h << 16; return v.f;
}
__device__ __forceinline__ u16 f2bf_bits(float f) {
    u32 u = __float_as_uint(f);
    u32 r = (u + 0x7fffu + ((u >> 16) & 1u)) >> 16;   // RNE
    return (u16)r;
}

// load 4 consecutive elements as fp32 (overloaded on source type)
__device__ __forceinline__ void load4(const float* p, float& a, float& b, float& c, float& d) {
    float4 v = *(const float4*)p; a = v.x; b = v.y; c = v.z; d = v.w;
}
__device__ __forceinline__ void load4(const u16* p, float& a, float& b, float& c, float& d) {
    uint2 w = *(const uint2*)p;
    a = bf2f((u16)(w.x & 0xffffu)); b = bf2f((u16)(w.x >> 16));
    c = bf2f((u16)(w.y & 0xffffu)); d = bf2f((u16)(w.y >> 16));
}
__device__ __forceinline__ void st1(float* p, float v) { *p = v; }
__device__ __forceinline__ void st1(u16* p, float v)   { *p = f2bf_bits(v); }

// ---------------------------------------------------------------------------
// LayerNorm stats over channel dim. x: (B, C, HW) fp32. One thread per (b,p):
// writes (mean, rstd) as float2. grid 256 blocks x 256 threads = B*HW.
// ---------------------------------------------------------------------------
__global__ __launch_bounds__(256) void lnstats_kernel(
    const float* __restrict__ x, float2* __restrict__ stats)
{
    int pos = blockIdx.x * 256 + threadIdx.x;
    int b = pos >> 12;
    int p = pos & (HWP - 1);
    const float* xp = x + (size_t)b * CCH * HWP + p;
    float s = 0.f, ss = 0.f;
    #pragma unroll 8
    for (int c = 0; c < CCH; ++c) {
        float v = xp[(size_t)c * HWP];
        s += v; ss += v * v;
    }
    float u = s * (1.0f / CCH);
    float var = ss * (1.0f / CCH) - u * u;
    stats[pos] = make_float2(u, rsqrtf(var + 1e-6f));
}

// ---------------------------------------------------------------------------
// Batched conv1x1 GEMM: Out[b][m][n] = sum_k Wt[m][k] * Bop[b][k][n]
//   Bop = lnw ? (lnw[k]*(X[b][k][n]-u[b][n])*r[b][n]+lnb[k]) : X[b][k][n]
//   (+ bias[m]) (+ res[b][m][n]),  K=256, N=4096, M in {256,512}
// Tile 64x64, BK=16, 256 threads, 4x4 per thread, fp32 accumulate.
// XT/OT in {float, u16(bf16)}. Wt/lnw/lnb/bias/res are fp32.
// grid: (N/64, M/64, B)
// ---------------------------------------------------------------------------
template<typename XT, typename OT>
__global__ __launch_bounds__(256) void conv1x1_gemm(
    const float* __restrict__ Wt, const XT* __restrict__ X,
    const float2* __restrict__ stats, const float* __restrict__ lnw,
    const float* __restrict__ lnb, OT* __restrict__ Out,
    const float* __restrict__ bias, const float* __restrict__ res, int M)
{
    __shared__ float As[16][68];   // [k][m]
    __shared__ float Bs[16][68];   // [k][n]
    int tid = threadIdx.x;
    int b  = blockIdx.z;
    int m0 = blockIdx.y << 6;
    int n0 = blockIdx.x << 6;
    const XT* Xb = X + (size_t)b * CCH * HWP;
    int tm = tid >> 4, tn = tid & 15;
    float acc[4][4];
    #pragma unroll
    for (int i = 0; i < 4; ++i)
        #pragma unroll
        for (int j = 0; j < 4; ++j) acc[i][j] = 0.f;

    int la_r = tid >> 2;           // A row (m) 0..63
    int la_c = (tid & 3) << 2;     // A col (k) 0,4,8,12
    int lb_r = tid >> 4;           // B row (k) 0..15
    int lb_c = (tid & 15) << 2;    // B col (n) 0..60

    for (int k0 = 0; k0 < CCH; k0 += 16) {
        float a0, a1, a2, a3;
        load4(Wt + (size_t)(m0 + la_r) * CCH + k0 + la_c, a0, a1, a2, a3);
        As[la_c + 0][la_r] = a0;
        As[la_c + 1][la_r] = a1;
        As[la_c + 2][la_r] = a2;
        As[la_c + 3][la_r] = a3;
        int k = k0 + lb_r;
        float x0, x1, x2, x3;
        load4(Xb + (size_t)k * HWP + n0 + lb_c, x0, x1, x2, x3);
        if (lnw) {
            float wk = lnw[k], bk = lnb[k];
            const float4* sp = (const float4*)(stats + (size_t)b * HWP + n0 + lb_c);
            float4 s01 = sp[0];   // u0,r0,u1,r1
            float4 s23 = sp[1];   // u2,r2,u3,r3
            x0 = wk * (x0 - s01.x) * s01.y + bk;
            x1 = wk * (x1 - s01.z) * s01.w + bk;
            x2 = wk * (x2 - s23.x) * s23.y + bk;
            x3 = wk * (x3 - s23.z) * s23.w + bk;
        }
        Bs[lb_r][lb_c + 0] = x0;
        Bs[lb_r][lb_c + 1] = x1;
        Bs[lb_r][lb_c + 2] = x2;
        Bs[lb_r][lb_c + 3] = x3;
        __syncthreads();
        #pragma unroll
        for (int kk = 0; kk < 16; ++kk) {
            float4 av = *(const float4*)&As[kk][tm << 2];
            float4 bv = *(const float4*)&Bs[kk][tn << 2];
            acc[0][0] += av.x * bv.x; acc[0][1] += av.x * bv.y;
            acc[0][2] += av.x * bv.z; acc[0][3] += av.x * bv.w;
            acc[1][0] += av.y * bv.x; acc[1][1] += av.y * bv.y;
            acc[1][2] += av.y * bv.z; acc[1][3] += av.y * bv.w;
            acc[2][0] += av.z * bv.x; acc[2][1] += av.z * bv.y;
            acc[2][2] += av.z * bv.z; acc[2][3] += av.z * bv.w;
            acc[3][0] += av.w * bv.x; acc[3][1] += av.w * bv.y;
            acc[3][2] += av.w * bv.z; acc[3][3] += av.w * bv.w;
        }
        __syncthreads();
    }

    size_t ob = (size_t)b * M * HWP;
    float bv4[4] = {0.f, 0.f, 0.f, 0.f};
    if (bias) {
        #pragma unroll
        for (int i = 0; i < 4; ++i) bv4[i] = bias[m0 + (tm << 2) + i];
    }
    #pragma unroll
    for (int i = 0; i < 4; ++i) {
        int m = m0 + (tm << 2) + i;
        OT* orow = Out + ob + (size_t)m * HWP + n0 + (tn << 2);
        const float* rrow = res ? (res + ob + (size_t)m * HWP + n0 + (tn << 2)) : (const float*)0;
        #pragma unroll
        for (int j = 0; j < 4; ++j) {
            float v = acc[i][j] + bv4[i];
            if (res) v += rrow[j];
            st1(&orow[j], v);
        }
    }
}

// ---------------------------------------------------------------------------
// Reciprocal L2 row norms over HW for q rows and the k-halves of kvt/kvd.
// grid: 3*B*C blocks, block 256. which = blockIdx.x / (B*C).
// ---------------------------------------------------------------------------
__global__ __launch_bounds__(256) void rownorm_kernel(
    const u16* __restrict__ q, const u16* __restrict__ kvt, const u16* __restrict__ kvd,
    float* __restrict__ rq, float* __restrict__ rkt, float* __restrict__ rkd)
{
    int tid = threadIdx.x;
    int idx = blockIdx.x;
    int which = idx >> 12;          // / (B*C) = 4096
    int bc = idx & 4095;
    int b = bc >> 8, c = bc & 255;
    const u16* row; float* out;
    if (which == 0) { row = q + (size_t)bc * HWP; out = rq + bc; }
    else {
        const u16* kv = (which == 1) ? kvt : kvd;
        row = kv + ((size_t)b * C2 + c) * HWP;    // k channels are 0..255
        out = ((which == 1) ? rkt : rkd) + bc;
    }
    float s = 0.f;
    for (int i = tid; i < HWP; i += 256) { float v = bf2f(row[i]); s += v * v; }
    #pragma unroll
    for (int off = 32; off > 0; off >>= 1) s += __shfl_down(s, off, 64);
    __shared__ float red[4];
    if ((tid & 63) == 0) red[tid >> 6] = s;
    __syncthreads();
    if (tid == 0) {
        float t = red[0] + red[1] + red[2] + red[3];
        out[0] = 1.0f / fmaxf(sqrtf(t), 1e-12f);
    }
}

// ---------------------------------------------------------------------------
// Scores + softmax: S[c,d] = rq[c]*rk[d] * sum_n Q[c,n]*K[d,n]  (K-dim = 4096)
// then row softmax -> P (64x64 fp32 per (which,b,h)) written to global.
// grid: (64 = B*NH, 2 = tex/dep), block 256, 4x4 acc per thread.
// ---------------------------------------------------------------------------
__global__ __launch_bounds__(256) void scores_kernel(
    const u16* __restrict__ q, const u16* __restrict__ kvt, const u16* __restrict__ kvd,
    const float* __restrict__ rq, const float* __restrict__ rkt, const float* __restrict__ rkd,
    float* __restrict__ P)
{
    __shared__ float Qs[64][68];   // [n_local][c]
    __shared__ float Ks[64][68];   // [n_local][d]
    int tid = threadIdx.x;
    int bh = blockIdx.x;           // 0..63
    int which = blockIdx.y;        // 0 tex, 1 dep
    int b = bh >> 2, h = bh & 3;
    const u16* Q = q + ((size_t)b * CCH + h * HD) * HWP;
    const u16* K = (which ? kvd : kvt) + ((size_t)b * C2 + h * HD) * HWP;
    const float* rqp = rq + b * CCH + h * HD;
    const float* rkp = (which ? rkd : rkt) + b * CCH + h * HD;

    int row = tid >> 2;            // 0..63
    int seg = (tid & 3) << 4;      // 0,16,32,48
    int tc = tid >> 4, td = tid & 15;
    float acc[4][4];
    #pragma unroll
    for (int i = 0; i < 4; ++i)
        #pragma unroll
        for (int j = 0; j < 4; ++j) acc[i][j] = 0.f;

    for (int n0 = 0; n0 < HWP; n0 += 64) {
        const u16* qp = Q + (size_t)row * HWP + n0 + seg;
        const u16* kp = K + (size_t)row * HWP + n0 + seg;
        uint4 q0 = *(const uint4*)qp;
        uint4 q1 = *(const uint4*)(qp + 8);
        uint4 k0 = *(const uint4*)kp;
        uint4 k1 = *(const uint4*)(kp + 8);
        Qs[seg + 0][row] = bf2f((u16)(q0.x & 0xffffu)); Qs[seg + 1][row] = bf2f((u16)(q0.x >> 16));
        Qs[seg + 2][row] = bf2f((u16)(q0.y & 0xffffu)); Qs[seg + 3][row] = bf2f((u16)(q0.y >> 16));
        Qs[seg + 4][row] = bf2f((u16)(q0.z & 0xffffu)); Qs[seg + 5][row] = bf2f((u16)(q0.z >> 16));
        Qs[seg + 6][row] = bf2f((u16)(q0.w & 0xffffu)); Qs[seg + 7][row] = bf2f((u16)(q0.w >> 16));
        Qs[seg + 8][row] = bf2f((u16)(q1.x & 0xffffu)); Qs[seg + 9][row] = bf2f((u16)(q1.x >> 16));
        Qs[seg +10][row] = bf2f((u16)(q1.y & 0xffffu)); Qs[seg +11][row] = bf2f((u16)(q1.y >> 16));
        Qs[seg +12][row] = bf2f((u16)(q1.z & 0xffffu)); Qs[seg +13][row] = bf2f((u16)(q1.z >> 16));
        Qs[seg +14][row] = bf2f((u16)(q1.w & 0xffffu)); Qs[seg +15][row] = bf2f((u16)(q1.w >> 16));
        Ks[seg + 0][row] = bf2f((u16)(k0.x & 0xffffu)); Ks[seg + 1][row] = bf2f((u16)(k0.x >> 16));
        Ks[seg + 2][row] = bf2f((u16)(k0.y & 0xffffu)); Ks[seg + 3][row] = bf2f((u16)(k0.y >> 16));
        Ks[seg + 4][row] = bf2f((u16)(k0.z & 0xffffu)); Ks[seg + 5][row] = bf2f((u16)(k0.z >> 16));
        Ks[seg + 6][row] = bf2f((u16)(k0.w & 0xffffu)); Ks[seg + 7][row] = bf2f((u16)(k0.w >> 16));
        Ks[seg + 8][row] = bf2f((u16)(k1.x & 0xffffu)); Ks[seg + 9][row] = bf2f((u16)(k1.x >> 16));
        Ks[seg +10][row] = bf2f((u16)(k1.y & 0xffffu)); Ks[seg +11][row] = bf2f((u16)(k1.y >> 16));
        Ks[seg +12][row] = bf2f((u16)(k1.z & 0xffffu)); Ks[seg +13][row] = bf2f((u16)(k1.z >> 16));
        Ks[seg +14][row] = bf2f((u16)(k1.w & 0xffffu)); Ks[seg +15][row] = bf2f((u16)(k1.w >> 16));
        __syncthreads();
        #pragma unroll 16
        for (int kk = 0; kk < 64; ++kk) {
            float4 qv = *(const float4*)&Qs[kk][tc << 2];
            float4 kv = *(const float4*)&Ks[kk][td << 2];
            acc[0][0] += qv.x * kv.x; acc[0][1] += qv.x * kv.y;
            acc[0][2] += qv.x * kv.z; acc[0][3] += qv.x * kv.w;
            acc[1][0] += qv.y * kv.x; acc[1][1] += qv.y * kv.y;
            acc[1][2] += qv.y * kv.z; acc[1][3] += qv.y * kv.w;
            acc[2][0] += qv.z * kv.x; acc[2][1] += qv.z * kv.y;
            acc[2][2] += qv.z * kv.z; acc[2][3] += qv.z * kv.w;
            acc[3][0] += qv.w * kv.x; acc[3][1] += qv.w * kv.y;
            acc[3][2] += qv.w * kv.z; acc[3][3] += qv.w * kv.w;
        }
        __syncthreads();
    }

    // scaled scores into LDS (reuse Qs as S[c][d])
    float rc[4], rd[4];
    #pragma unroll
    for (int i = 0; i < 4; ++i) rc[i] = rqp[(tc << 2) + i];
    #pragma unroll
    for (int j = 0; j < 4; ++j) rd[j] = rkp[(td << 2) + j];
    #pragma unroll
    for (int i = 0; i < 4; ++i)
        #pragma unroll
        for (int j = 0; j < 4; ++j)
            Qs[(tc << 2) + i][(td << 2) + j] = acc[i][j] * rc[i] * rd[j];
    __syncthreads();

    if (tid < 64) {
        float mx = -1e30f;
        #pragma unroll 8
        for (int d = 0; d < 64; ++d) mx = fmaxf(mx, Qs[tid][d]);
        float ssum = 0.f;
        #pragma unroll 8
        for (int d = 0; d < 64; ++d) {
            float e = expf(Qs[tid][d] - mx);
            Qs[tid][d] = e; ssum += e;
        }
        float inv = 1.0f / ssum;
        float* dst = P + ((size_t)which * 64 + bh) * 4096 + tid * 64;
        #pragma unroll 8
        for (int d = 0; d < 64; ++d) dst[d] = Qs[tid][d] * inv;
    }
}

// ---------------------------------------------------------------------------
// qkv[b,h,c,n] = g*sum_d Pt[c,d]*Vt[d,n] + (1-g)*sum_d Pd[c,d]*Vd[d,n]
// One thread per n; V columns (64 each) in registers; P in LDS (broadcast).
// grid: (HW/256, B*NH), block 256.
// ---------------------------------------------------------------------------
__global__ __launch_bounds__(256) void attnout_kernel(
    const u16* __restrict__ kvt, const u16* __restrict__ kvd,
    const float* __restrict__ P, const float* __restrict__ attn_scale,
    u16* __restrict__ qkv)
{
    __shared__ __align__(16) float Pt[4096];
    __shared__ __align__(16) float Pd[4096];
    int tid = threadIdx.x;
    int bh = blockIdx.y; int b = bh >> 2, h = bh & 3;
    int n = (blockIdx.x << 8) + tid;
    const float* Pts = P + (size_t)bh * 4096;
    const float* Pds = P + (size_t)(64 + bh) * 4096;
    for (int i = tid; i < 4096; i += 256) { Pt[i] = Pts[i]; Pd[i] = Pds[i]; }
    const u16* Vt = kvt + ((size_t)b * C2 + CCH + h * HD) * HWP + n;
    const u16* Vd = kvd + ((size_t)b * C2 + CCH + h * HD) * HWP + n;
    float vt[64], vd[64];
    #pragma unroll
    for (int d = 0; d < 64; ++d) {
        vt[d] = bf2f(Vt[(size_t)d * HWP]);
        vd[d] = bf2f(Vd[(size_t)d * HWP]);
    }
    float g = 1.0f / (1.0f + expf(-attn_scale[h]));
    float gi = 1.0f - g;
    __syncthreads();
    u16* op = qkv + ((size_t)b * CCH + h * HD) * HWP + n;
    for (int c = 0; c < 64; ++c) {
        const float* pr  = &Pt[c * 64];
        const float* pdr = &Pd[c * 64];
        float a = 0.f, bb = 0.f;
        #pragma unroll
        for (int d4 = 0; d4 < 64; d4 += 4) {
            float4 p4  = *(const float4*)(pr + d4);
            float4 p4d = *(const float4*)(pdr + d4);
            a  += p4.x * vt[d4] + p4.y * vt[d4+1] + p4.z * vt[d4+2] + p4.w * vt[d4+3];
            bb += p4d.x * vd[d4] + p4d.y * vd[d4+1] + p4d.z * vd[d4+2] + p4d.w * vd[d4+3];
        }
        op[(size_t)c * HWP] = f2bf_bits(g * a + gi * bb);
    }
}

// ---------------------------------------------------------------------------
// Depthwise 3x3 (SAME, cross-correlation per XLA) + exact GELU.
// grid: B*C*HW/256, block 256, one thread per output element.
// ---------------------------------------------------------------------------
__global__ __launch_bounds__(256) void dwgelu_kernel(
    const u16* __restrict__ y1, const float* __restrict__ dww, u16* __restrict__ y2)
{
    size_t idx = (size_t)blockIdx.x * 256 + threadIdx.x;
    int p = (int)(idx & 4095);
    size_t bc = idx >> 12;
    int c = (int)(bc & 255);
    int hh = p >> 6, ww = p & 63;
    const u16* base = y1 + bc * (size_t)HWP;
    float acc = 0.f;
    #pragma unroll
    for (int dy = -1; dy <= 1; ++dy) {
        int y = hh + dy;
        if ((unsigned)y >= 64u) continue;
        #pragma unroll
        for (int dx = -1; dx <= 1; ++dx) {
            int x = ww + dx;
            if ((unsigned)x >= 64u) continue;
            acc += bf2f(base[y * 64 + x]) * dww[c * 9 + (dy + 1) * 3 + (dx + 1)];
        }
    }
    float ge = 0.5f * acc * (1.0f + erff(acc * 0.70710678118654752f));
    y2[idx] = f2bf_bits(ge);
}

// ---------------------------------------------------------------------------
// I/O is fp32 (per the reference's dtypes). Big intermediates bf16 in ws.
// Workspace: qbuf 32 MB | kvt 64 MB | kvd 64 MB | stats 0.5 MB | norms 48 KB
//            | P 2 MB = ~162.6 MB (< 256 MiB).
// x lives in d_out (fp32); y1 aliases kvt; y2 aliases kvd; qkv aliases qbuf.
// ---------------------------------------------------------------------------
extern "C" void kernel_launch(void* const* d_in, const int* in_sizes, int n_in,
                              void* d_out, int out_size, void* d_ws, size_t ws_size,
                              hipStream_t stream)
{
    const float* img    = (const float*)d_in[0];
    const float* tex    = (const float*)d_in[1];
    const float* dep    = (const float*)d_in[2];
    const float* qnw    = (const float*)d_in[3];
    const float* qnb    = (const float*)d_in[4];
    const float* kvnw   = (const float*)d_in[5];
    const float* kvnb   = (const float*)d_in[6];
    const float* ascale = (const float*)d_in[7];
    const float* qpw    = (const float*)d_in[8];
    const float* kvpw   = (const float*)d_in[9];
    const float* opw    = (const float*)d_in[10];
    const float* opb    = (const float*)d_in[11];
    const float* fnw    = (const float*)d_in[12];
    const float* fnb    = (const float*)d_in[13];
    const float* fc1w   = (const float*)d_in[14];
    const float* dww    = (const float*)d_in[15];
    const float* fc2w   = (const float*)d_in[16];
    float* out = (float*)d_out;

    const size_t TEN = (size_t)BQ * CCH * HWP;   // 16,777,216 elements
    char* w = (char*)d_ws;
    u16* qbuf = (u16*)w; w += TEN * 2;           // q bf16, later qkv (aliased)
    u16* kvt  = (u16*)w; w += TEN * 4;           // (B,512,HW) bf16; later y1
    u16* kvd  = (u16*)w; w += TEN * 4;           // (B,512,HW) bf16; later y2
    float2* stats = (float2*)w; w += (size_t)BQ * HWP * 8;        // 512 KB
    float* rq  = (float*)w; w += (size_t)BQ * CCH * 4;
    float* rkt = (float*)w; w += (size_t)BQ * CCH * 4;
    float* rkd = (float*)w; w += (size_t)BQ * CCH * 4;
    float* P   = (float*)w; w += (size_t)2 * BQ * NHH * HD * HD * 4;  // 2 MB
    u16* qkv = qbuf;     // alias: q dead after scores_kernel
    u16* y1  = kvt;      // alias: kvt dead after attnout_kernel
    u16* y2  = kvd;      // alias: kvd dead after attnout_kernel
    float* x = out;      // x lives in d_out (in-place residual at the end)

    dim3 blk(256);
    const float* NO_F = (const float*)0;

    // q = q_proj(ln(img))                         [fp32 in -> bf16 out]
    lnstats_kernel<<<256, blk, 0, stream>>>(img, stats);
    conv1x1_gemm<float, u16><<<dim3(64, 4, 16), blk, 0, stream>>>(
        qpw, img, stats, qnw, qnb, qbuf, NO_F, NO_F, 256);
    // kvt = kv_proj(ln(tex)), kvd = kv_proj(ln(dep))
    lnstats_kernel<<<256, blk, 0, stream>>>(tex, stats);
    conv1x1_gemm<float, u16><<<dim3(64, 8, 16), blk, 0, stream>>>(
        kvpw, tex, stats, kvnw, kvnb, kvt, NO_F, NO_F, 512);
    lnstats_kernel<<<256, blk, 0, stream>>>(dep, stats);
    conv1x1_gemm<float, u16><<<dim3(64, 8, 16), blk, 0, stream>>>(
        kvpw, dep, stats, kvnw, kvnb, kvd, NO_F, NO_F, 512);
    // attention
    rownorm_kernel<<<3 * 4096, blk, 0, stream>>>(qbuf, kvt, kvd, rq, rkt, rkd);
    scores_kernel<<<dim3(64, 2), blk, 0, stream>>>(qbuf, kvt, kvd, rq, rkt, rkd, P);
    attnout_kernel<<<dim3(16, 64), blk, 0, stream>>>(kvt, kvd, P, ascale, qkv);
    // x = img + o_proj(qkv) + o_proj_b            [bf16 in -> fp32 out in d_out]
    conv1x1_gemm<u16, float><<<dim3(64, 4, 16), blk, 0, stream>>>(
        opw, qkv, stats, NO_F, NO_F, x, opb, img, 256);
    // FFN: y1 = fc1(ln(x)); y2 = gelu(dw3x3(y1)); out = x + fc2(y2)
    lnstats_kernel<<<256, blk, 0, stream>>>(x, stats);
    conv1x1_gemm<float, u16><<<dim3(64, 4, 16), blk, 0, stream>>>(
        fc1w, x, stats, fnw, fnb, y1, NO_F, NO_F, 256);
    dwgelu_kernel<<<65536, blk, 0, stream>>>(y1, dww, y2);
    conv1x1_gemm<u16, float><<<dim3(64, 4, 16), blk, 0, stream>>>(
        fc2w, y2, stats, NO_F, NO_F, out, NO_F, x, 256);
}

// Round 4
// 1215.305 us; speedup vs baseline: 1.5367x; 1.5367x over previous
//
#include <hip/hip_runtime.h>

// Problem constants
#define BQ   16
#define CCH  256
#define HWP  4096   // H*W

typedef unsigned short u16;
typedef unsigned int   u32;
typedef __attribute__((ext_vector_type(8))) short bf16x8;   // 8 bf16 (4 VGPRs)
typedef __attribute__((ext_vector_type(4))) float f32x4;    // MFMA C/D

__device__ __forceinline__ float bf2f(u16 h) {
    union { u32 u; float f; } v; v.u = (u32)h << 16; return v.f;
}
__device__ __forceinline__ u16 f2bf_bits(float f) {
    u32 u = __float_as_uint(f);
    u32 r = (u + 0x7fffu + ((u >> 16) & 1u)) >> 16;   // RNE
    return (u16)r;
}
__device__ __forceinline__ u32 pack2(float a, float b) {
    return (u32)f2bf_bits(a) | ((u32)f2bf_bits(b) << 16);
}

// ---------------------------------------------------------------------------
// fp32 -> bf16 weight convert. n4 = count/4.
// ---------------------------------------------------------------------------
__global__ __launch_bounds__(256) void f2bf_kernel(
    const float* __restrict__ src, u16* __restrict__ dst, int n4)
{
    int i = blockIdx.x * 256 + threadIdx.x;
    if (i < n4) {
        float4 v = ((const float4*)src)[i];
        uint2 p; p.x = pack2(v.x, v.y); p.y = pack2(v.z, v.w);
        ((uint2*)dst)[i] = p;
    }
}

// ---------------------------------------------------------------------------
// LayerNorm over C + transpose: x fp32 [b][c][n] -> outT bf16 [b][n][c].
// Thread per (b,n); strided reads coalesced across threads; 512B row writes.
// grid 256, block 256.
// ---------------------------------------------------------------------------
__global__ __launch_bounds__(256) void ln_t_f32(
    const float* __restrict__ x, const float* __restrict__ wgt,
    const float* __restrict__ bias, u16* __restrict__ outT)
{
    __shared__ float sw[CCH], sb[CCH];
    int tid = threadIdx.x;
    sw[tid] = wgt[tid]; sb[tid] = bias[tid];
    __syncthreads();
    int pos = blockIdx.x * 256 + tid;
    int b = pos >> 12, n = pos & 4095;
    const float* xp = x + (size_t)b * CCH * HWP + n;
    float s = 0.f, ss = 0.f;
    #pragma unroll 8
    for (int c = 0; c < CCH; ++c) { float v = xp[(size_t)c * HWP]; s += v; ss += v * v; }
    float u = s * (1.0f / CCH);
    float r = rsqrtf(ss * (1.0f / CCH) - u * u + 1e-6f);
    u16* op = outT + ((size_t)b * HWP + n) * CCH;
    for (int c0 = 0; c0 < CCH; c0 += 8) {
        u16 tmp[8];
        #pragma unroll
        for (int j = 0; j < 8; ++j) {
            float v = xp[(size_t)(c0 + j) * HWP];
            tmp[j] = f2bf_bits(sw[c0 + j] * (v - u) * r + sb[c0 + j]);
        }
        *(uint4*)(op + c0) = *(uint4*)tmp;
    }
}

// Same, but input already bf16 T-layout [b][n][c] (used for LN of x).
__global__ __launch_bounds__(256) void ln_t_bf16T(
    const u16* __restrict__ xT, const float* __restrict__ wgt,
    const float* __restrict__ bias, u16* __restrict__ outT)
{
    __shared__ float sw[CCH], sb[CCH];
    int tid = threadIdx.x;
    sw[tid] = wgt[tid]; sb[tid] = bias[tid];
    __syncthreads();
    int pos = blockIdx.x * 256 + tid;
    int b = pos >> 12, n = pos & 4095;
    const u16* xp = xT + ((size_t)b * HWP + n) * CCH;
    float s = 0.f, ss = 0.f, vals[8];
    for (int c0 = 0; c0 < CCH; c0 += 8) {
        uint4 w4 = *(const uint4*)(xp + c0);
        const u16* ph = (const u16*)&w4;
        #pragma unroll
        for (int j = 0; j < 8; ++j) { float v = bf2f(ph[j]); s += v; ss += v * v; }
    }
    float u = s * (1.0f / CCH);
    float r = rsqrtf(ss * (1.0f / CCH) - u * u + 1e-6f);
    u16* op = outT + ((size_t)b * HWP + n) * CCH;
    for (int c0 = 0; c0 < CCH; c0 += 8) {
        uint4 w4 = *(const uint4*)(xp + c0);
        const u16* ph = (const u16*)&w4;
        u16 tmp[8];
        #pragma unroll
        for (int j = 0; j < 8; ++j)
            tmp[j] = f2bf_bits(sw[c0 + j] * (bf2f(ph[j]) - u) * r + sb[c0 + j]);
        *(uint4*)(op + c0) = *(uint4*)tmp;
    }
    (void)vals;
}

// ---------------------------------------------------------------------------
// MFMA GEMM: Out[b][m][n] = sum_k Wb[m][k] * XT[b][n][k]   (K=256)
// 128x128 block tile, 4 waves (2x2), each wave 64x64 = 4x4 MFMA 16x16x32.
// Operands straight from global (L2 serves reuse); no LDS, no barriers.
// MODE 0: orig bf16 out [b][256][4096]           (q, fc1)
// MODE 1: m<256 -> orig bf16 K; m>=256 -> T bf16 V [b][n][256]   (kv)
// MODE 2: +bias +resF(img fp32 orig); fp32 orig out_f (=x in d_out) AND
//         T bf16 outB (=xT)                       (o_proj)
// MODE 3: +resF (x, fp32 orig = d_out); fp32 orig out_f (d_out)   (fc2)
// grid: (32, M/128, 16)
// ---------------------------------------------------------------------------
template<int MODE>
__global__ __launch_bounds__(256) void gemmT(
    const u16* __restrict__ Wb, const u16* __restrict__ XT,
    u16* __restrict__ outA, u16* __restrict__ outB,
    float* __restrict__ outF, const float* __restrict__ bias,
    const float* __restrict__ resF)
{
    int tid = threadIdx.x;
    int w = tid >> 6, lane = tid & 63;
    int lr = lane & 15, quad = lane >> 4;
    int wm = w >> 1, wn = w & 1;
    int b  = blockIdx.z;
    int m0 = blockIdx.y * 128 + wm * 64;
    int n0 = blockIdx.x * 128 + wn * 64;

    f32x4 zz = {0.f, 0.f, 0.f, 0.f};
    f32x4 acc[4][4];
    #pragma unroll
    for (int i = 0; i < 4; ++i)
        #pragma unroll
        for (int j = 0; j < 4; ++j) acc[i][j] = zz;

    const u16* Ab = Wb + (size_t)(m0 + lr) * CCH + quad * 8;
    const u16* Bb = XT + ((size_t)b * HWP + n0 + lr) * CCH + quad * 8;

    #pragma unroll
    for (int k0 = 0; k0 < 256; k0 += 32) {
        bf16x8 a[4], bb[4];
        #pragma unroll
        for (int mi = 0; mi < 4; ++mi) a[mi]  = *(const bf16x8*)(Ab + (size_t)mi * 16 * CCH + k0);
        #pragma unroll
        for (int nj = 0; nj < 4; ++nj) bb[nj] = *(const bf16x8*)(Bb + (size_t)nj * 16 * CCH + k0);
        #pragma unroll
        for (int mi = 0; mi < 4; ++mi)
            #pragma unroll
            for (int nj = 0; nj < 4; ++nj)
                acc[mi][nj] = __builtin_amdgcn_mfma_f32_16x16x32_bf16(a[mi], bb[nj], acc[mi][nj], 0, 0, 0);
    }

    #pragma unroll
    for (int mi = 0; mi < 4; ++mi) {
        int mbase = m0 + mi * 16 + quad * 4;   // 4 consecutive m via reg idx
        #pragma unroll
        for (int nj = 0; nj < 4; ++nj) {
            int n = n0 + nj * 16 + lr;
            if (MODE == 0 || (MODE == 1 && m0 < 256)) {
                size_t base = ((size_t)b * CCH + mbase) * HWP + n;
                #pragma unroll
                for (int r = 0; r < 4; ++r)
                    outA[base + (size_t)r * HWP] = f2bf_bits(acc[mi][nj][r]);
            } else if (MODE == 1) {            // V-half -> T layout
                uint2 p;
                p.x = pack2(acc[mi][nj][0], acc[mi][nj][1]);
                p.y = pack2(acc[mi][nj][2], acc[mi][nj][3]);
                *(uint2*)(outB + ((size_t)b * HWP + n) * CCH + (mbase - 256)) = p;
            } else if (MODE == 2) {
                float v[4];
                size_t rb = ((size_t)b * CCH + mbase) * HWP + n;
                #pragma unroll
                for (int r = 0; r < 4; ++r) {
                    v[r] = acc[mi][nj][r] + bias[mbase + r] + resF[rb + (size_t)r * HWP];
                    outF[rb + (size_t)r * HWP] = v[r];
                }
                uint2 p; p.x = pack2(v[0], v[1]); p.y = pack2(v[2], v[3]);
                *(uint2*)(outB + ((size_t)b * HWP + n) * CCH + mbase) = p;
            } else {                           // MODE 3
                size_t rb = ((size_t)b * CCH + mbase) * HWP + n;
                #pragma unroll
                for (int r = 0; r < 4; ++r)
                    outF[rb + (size_t)r * HWP] = acc[mi][nj][r] + resF[rb + (size_t)r * HWP];
            }
        }
    }
}

// ---------------------------------------------------------------------------
// Reciprocal L2 row norms over HW for q and K rows (all orig layout bf16).
// grid: 3*B*C blocks, block 256.
// ---------------------------------------------------------------------------
__global__ __launch_bounds__(256) void rownorm_kernel(
    const u16* __restrict__ q, const u16* __restrict__ Ktex, const u16* __restrict__ Kdep,
    float* __restrict__ rq, float* __restrict__ rkt, float* __restrict__ rkd)
{
    int tid = threadIdx.x;
    int idx = blockIdx.x;
    int which = idx >> 12;
    int bc = idx & 4095;
    const u16* row = (which == 0 ? q : which == 1 ? Ktex : Kdep) + (size_t)bc * HWP;
    float* out = (which == 0 ? rq : which == 1 ? rkt : rkd) + bc;
    float s = 0.f;
    for (int i = tid; i < HWP; i += 256) { float v = bf2f(row[i]); s += v * v; }
    #pragma unroll
    for (int off = 32; off > 0; off >>= 1) s += __shfl_down(s, off, 64);
    __shared__ float red[4];
    if ((tid & 63) == 0) red[tid >> 6] = s;
    __syncthreads();
    if (tid == 0) {
        float t = red[0] + red[1] + red[2] + red[3];
        out[0] = 1.0f / fmaxf(sqrtf(t), 1e-12f);
    }
}

// ---------------------------------------------------------------------------
// Scores partial (MFMA): Sp[which][bh][nc][c][d] = sum_{n in chunk} q[c][n]k[d][n]
// grid (8 nchunk, 64 bh, 2 which), block 256 (wave w -> c-tile w).
// ---------------------------------------------------------------------------
__global__ __launch_bounds__(256) void scores_mfma(
    const u16* __restrict__ q, const u16* __restrict__ Ktex, const u16* __restrict__ Kdep,
    float* __restrict__ Sp)
{
    int tid = threadIdx.x;
    int w = tid >> 6, lane = tid & 63;
    int lr = lane & 15, quad = lane >> 4;
    int nc = blockIdx.x, bh = blockIdx.y, which = blockIdx.z;
    int b = bh >> 2, h = bh & 3;
    const u16* Q = q + ((size_t)b * CCH + h * 64) * HWP;
    const u16* K = (which ? Kdep : Ktex) + ((size_t)b * CCH + h * 64) * HWP;

    f32x4 zz = {0.f, 0.f, 0.f, 0.f};
    f32x4 acc[4] = {zz, zz, zz, zz};
    const u16* Ab = Q + (size_t)(w * 16 + lr) * HWP + nc * 512 + quad * 8;
    const u16* Bb = K + (size_t)lr * HWP + nc * 512 + quad * 8;

    #pragma unroll 4
    for (int s = 0; s < 16; ++s) {
        int off = s * 32;
        bf16x8 a = *(const bf16x8*)(Ab + off);
        #pragma unroll
        for (int dj = 0; dj < 4; ++dj) {
            bf16x8 kb = *(const bf16x8*)(Bb + (size_t)dj * 16 * HWP + off);
            acc[dj] = __builtin_amdgcn_mfma_f32_16x16x32_bf16(a, kb, acc[dj], 0, 0, 0);
        }
    }
    float* out = Sp + (((size_t)(which * 64 + bh) * 8 + nc) * 4096);
    #pragma unroll
    for (int dj = 0; dj < 4; ++dj)
        #pragma unroll
        for (int r = 0; r < 4; ++r)
            out[(w * 16 + quad * 4 + r) * 64 + dj * 16 + lr] = acc[dj][r];
}

// ---------------------------------------------------------------------------
// Reduce partials + scale (rq*rk) + softmax + gate fold -> P bf16 [2][bh][c][d]
// grid 64 (bh), block 256.
// ---------------------------------------------------------------------------
__global__ __launch_bounds__(256) void softmax_kernel(
    const float* __restrict__ Sp, const float* __restrict__ rq,
    const float* __restrict__ rkt, const float* __restrict__ rkd,
    const float* __restrict__ ascale, u16* __restrict__ Pp)
{
    __shared__ float S[64][65];
    int tid = threadIdx.x;
    int bh = blockIdx.x; int b = bh >> 2, h = bh & 3;
    float g = 1.0f / (1.0f + expf(-ascale[h]));
    for (int which = 0; which < 2; ++which) {
        const float* base = Sp + ((size_t)(which * 64 + bh) * 8) * 4096;
        const float* rk  = (which ? rkd : rkt) + b * CCH + h * 64;
        const float* rqp = rq + b * CCH + h * 64;
        float gain = which ? (1.0f - g) : g;
        __syncthreads();
        for (int i = tid; i < 4096; i += 256) {
            float s = 0.f;
            #pragma unroll
            for (int p = 0; p < 8; ++p) s += base[(size_t)p * 4096 + i];
            S[i >> 6][i & 63] = s * rqp[i >> 6] * rk[i & 63];
        }
        __syncthreads();
        if (tid < 64) {
            float mx = -1e30f;
            #pragma unroll 8
            for (int d = 0; d < 64; ++d) mx = fmaxf(mx, S[tid][d]);
            float sum = 0.f;
            #pragma unroll 8
            for (int d = 0; d < 64; ++d) { float e = expf(S[tid][d] - mx); S[tid][d] = e; sum += e; }
            float inv = gain / sum;
            u16* dst = Pp + ((size_t)(which * 64 + bh) * 64 + tid) * 64;
            #pragma unroll 8
            for (int d = 0; d < 64; ++d) dst[d] = f2bf_bits(S[tid][d] * inv);
        }
    }
}

// ---------------------------------------------------------------------------
// PV (MFMA): qkvT[b][n][h*64+c] = sum_d Pt[c][d]VtT[n][d] + Pd[c][d]VdT[n][d]
// (gates pre-folded into P). grid (16 nchunk, 64 bh), block 256.
// ---------------------------------------------------------------------------
__global__ __launch_bounds__(256) void pv_mfma(
    const u16* __restrict__ Pp, const u16* __restrict__ VtexT,
    const u16* __restrict__ VdepT, u16* __restrict__ qkvT)
{
    int tid = threadIdx.x;
    int w = tid >> 6, lane = tid & 63;
    int lr = lane & 15, quad = lane >> 4;
    int nc = blockIdx.x, bh = blockIdx.y;
    int b = bh >> 2, h = bh & 3;
    int n0 = nc * 256 + w * 64;

    f32x4 zz = {0.f, 0.f, 0.f, 0.f};
    f32x4 acc[4][4];
    #pragma unroll
    for (int i = 0; i < 4; ++i)
        #pragma unroll
        for (int j = 0; j < 4; ++j) acc[i][j] = zz;

    #pragma unroll
    for (int src = 0; src < 2; ++src) {
        const u16* P  = Pp + ((size_t)(src * 64 + bh) * 64) * 64;
        const u16* VT = (src ? VdepT : VtexT);
        const u16* Vb = VT + ((size_t)b * HWP + n0 + lr) * CCH + h * 64 + quad * 8;
        #pragma unroll
        for (int ks = 0; ks < 2; ++ks) {
            bf16x8 a[4], vv[4];
            #pragma unroll
            for (int ci = 0; ci < 4; ++ci)
                a[ci] = *(const bf16x8*)(P + (size_t)(ci * 16 + lr) * 64 + ks * 32 + quad * 8);
            #pragma unroll
            for (int nj = 0; nj < 4; ++nj)
                vv[nj] = *(const bf16x8*)(Vb + (size_t)nj * 16 * CCH + ks * 32);
            #pragma unroll
            for (int ci = 0; ci < 4; ++ci)
                #pragma unroll
                for (int nj = 0; nj < 4; ++nj)
                    acc[ci][nj] = __builtin_amdgcn_mfma_f32_16x16x32_bf16(a[ci], vv[nj], acc[ci][nj], 0, 0, 0);
        }
    }
    #pragma unroll
    for (int ci = 0; ci < 4; ++ci)
        #pragma unroll
        for (int nj = 0; nj < 4; ++nj) {
            int n = n0 + nj * 16 + lr;
            uint2 p;
            p.x = pack2(acc[ci][nj][0], acc[ci][nj][1]);
            p.y = pack2(acc[ci][nj][2], acc[ci][nj][3]);
            *(uint2*)(qkvT + ((size_t)b * HWP + n) * CCH + h * 64 + ci * 16 + quad * 4) = p;
        }
}

// ---------------------------------------------------------------------------
// Depthwise 3x3 + exact GELU; input y1 orig bf16 [b][c][n], output y2T [b][n][c].
// Block: 64 n-positions x 4 c-quarters. grid 1024.
// ---------------------------------------------------------------------------
__global__ __launch_bounds__(256) void dwgelu_T(
    const u16* __restrict__ y1, const float* __restrict__ dww, u16* __restrict__ y2T)
{
    __shared__ float sdw[2304];
    int tid = threadIdx.x;
    for (int i = tid; i < 2304; i += 256) sdw[i] = dww[i];
    __syncthreads();
    int nl = tid & 63, cq = tid >> 6;
    int gidx = blockIdx.x * 64 + nl;
    int b = gidx >> 12, n = gidx & 4095;
    int hh = n >> 6, ww = n & 63;
    const u16* base = y1 + (size_t)b * CCH * HWP;
    u16* orow = y2T + ((size_t)b * HWP + n) * CCH + cq * 64;
    for (int c0 = 0; c0 < 64; c0 += 8) {
        u16 tmp[8];
        #pragma unroll
        for (int j = 0; j < 8; ++j) {
            int c = cq * 64 + c0 + j;
            const u16* yc = base + (size_t)c * HWP;
            const float* wc = &sdw[c * 9];
            float acc = 0.f;
            #pragma unroll
            for (int dy = -1; dy <= 1; ++dy) {
                int y = hh + dy;
                if ((unsigned)y >= 64u) continue;
                #pragma unroll
                for (int dx = -1; dx <= 1; ++dx) {
                    int x = ww + dx;
                    if ((unsigned)x >= 64u) continue;
                    acc += bf2f(yc[y * 64 + x]) * wc[(dy + 1) * 3 + (dx + 1)];
                }
            }
            tmp[j] = f2bf_bits(0.5f * acc * (1.0f + erff(acc * 0.70710678118654752f)));
        }
        *(uint4*)(orow + c0) = *(uint4*)tmp;
    }
}

// ---------------------------------------------------------------------------
// Workspace (~210 MB): lnT 32 | q 32 | Ktex 32 | VtexT 32 | Kdep 32 | VdepT 32
//   | Sp 16 | Pp 1 | norms 48K | wbf 784K.  Aliases: qkvT=lnT (after dep kv);
//   xT=q (after scores); y1=Ktex (after scores); y2T=VtexT (after PV).
// ---------------------------------------------------------------------------
extern "C" void kernel_launch(void* const* d_in, const int* in_sizes, int n_in,
                              void* d_out, int out_size, void* d_ws, size_t ws_size,
                              hipStream_t stream)
{
    const float* img    = (const float*)d_in[0];
    const float* tex    = (const float*)d_in[1];
    const float* dep    = (const float*)d_in[2];
    const float* qnw    = (const float*)d_in[3];
    const float* qnb    = (const float*)d_in[4];
    const float* kvnw   = (const float*)d_in[5];
    const float* kvnb   = (const float*)d_in[6];
    const float* ascale = (const float*)d_in[7];
    const float* qpw    = (const float*)d_in[8];
    const float* kvpw   = (const float*)d_in[9];
    const float* opw    = (const float*)d_in[10];
    const float* opb    = (const float*)d_in[11];
    const float* fnw    = (const float*)d_in[12];
    const float* fnb    = (const float*)d_in[13];
    const float* fc1w   = (const float*)d_in[14];
    const float* dww    = (const float*)d_in[15];
    const float* fc2w   = (const float*)d_in[16];
    float* out = (float*)d_out;

    const size_t TEN = (size_t)BQ * CCH * HWP;   // 16,777,216
    char* p = (char*)d_ws;
    u16* lnT   = (u16*)p; p += TEN * 2;
    u16* qbuf  = (u16*)p; p += TEN * 2;
    u16* Ktex  = (u16*)p; p += TEN * 2;
    u16* VtexT = (u16*)p; p += TEN * 2;
    u16* Kdep  = (u16*)p; p += TEN * 2;
    u16* VdepT = (u16*)p; p += TEN * 2;
    float* Sp  = (float*)p; p += (size_t)8 * 2 * 64 * 4096 * 4;   // 16 MB
    u16* Pp    = (u16*)p;  p += (size_t)2 * 64 * 64 * 64 * 2;     // 1 MB
    float* rq  = (float*)p; p += (size_t)BQ * CCH * 4;
    float* rkt = (float*)p; p += (size_t)BQ * CCH * 4;
    float* rkd = (float*)p; p += (size_t)BQ * CCH * 4;
    u16* wq  = (u16*)p; p += 65536 * 2;
    u16* wkv = (u16*)p; p += 131072 * 2;
    u16* wo  = (u16*)p; p += 65536 * 2;
    u16* wf1 = (u16*)p; p += 65536 * 2;
    u16* wf2 = (u16*)p; p += 65536 * 2;
    u16* qkvT = lnT;     // alias
    u16* xT   = qbuf;    // alias
    u16* y1   = Ktex;    // alias
    u16* y2T  = VtexT;   // alias

    dim3 blk(256);
    // weight converts
    f2bf_kernel<<<64,  blk, 0, stream>>>(qpw,  wq,  16384);
    f2bf_kernel<<<128, blk, 0, stream>>>(kvpw, wkv, 32768);
    f2bf_kernel<<<64,  blk, 0, stream>>>(opw,  wo,  16384);
    f2bf_kernel<<<64,  blk, 0, stream>>>(fc1w, wf1, 16384);
    f2bf_kernel<<<64,  blk, 0, stream>>>(fc2w, wf2, 16384);
    // projections
    ln_t_f32<<<256, blk, 0, stream>>>(img, qnw, qnb, lnT);
    gemmT<0><<<dim3(32, 2, 16), blk, 0, stream>>>(wq, lnT, qbuf, (u16*)0, (float*)0, (const float*)0, (const float*)0);
    ln_t_f32<<<256, blk, 0, stream>>>(tex, kvnw, kvnb, lnT);
    gemmT<1><<<dim3(32, 4, 16), blk, 0, stream>>>(wkv, lnT, Ktex, VtexT, (float*)0, (const float*)0, (const float*)0);
    ln_t_f32<<<256, blk, 0, stream>>>(dep, kvnw, kvnb, lnT);
    gemmT<1><<<dim3(32, 4, 16), blk, 0, stream>>>(wkv, lnT, Kdep, VdepT, (float*)0, (const float*)0, (const float*)0);
    // attention
    rownorm_kernel<<<3 * 4096, blk, 0, stream>>>(qbuf, Ktex, Kdep, rq, rkt, rkd);
    scores_mfma<<<dim3(8, 64, 2), blk, 0, stream>>>(qbuf, Ktex, Kdep, Sp);
    softmax_kernel<<<64, blk, 0, stream>>>(Sp, rq, rkt, rkd, ascale, Pp);
    pv_mfma<<<dim3(16, 64), blk, 0, stream>>>(Pp, VtexT, VdepT, qkvT);
    // x = img + o_proj(qkv) + b  (fp32 in d_out, bf16 xT in ws)
    gemmT<2><<<dim3(32, 2, 16), blk, 0, stream>>>(wo, qkvT, (u16*)0, xT, out, opb, img);
    // FFN
    ln_t_bf16T<<<256, blk, 0, stream>>>(xT, fnw, fnb, lnT);
    gemmT<0><<<dim3(32, 2, 16), blk, 0, stream>>>(wf1, lnT, y1, (u16*)0, (float*)0, (const float*)0, (const float*)0);
    dwgelu_T<<<1024, blk, 0, stream>>>(y1, dww, y2T);
    gemmT<3><<<dim3(32, 2, 16), blk, 0, stream>>>(wf2, y2T, (u16*)0, (u16*)0, out, (const float*)0, out);
}

// Round 5
// 1074.855 us; speedup vs baseline: 1.7375x; 1.1307x over previous
//
#include <hip/hip_runtime.h>

// Problem constants
#define BQ   16
#define CCH  256
#define HWP  4096   // H*W

typedef unsigned short u16;
typedef unsigned int   u32;
typedef __attribute__((ext_vector_type(8))) short bf16x8;   // 8 bf16 (4 VGPRs)
typedef __attribute__((ext_vector_type(4))) float f32x4;    // MFMA C/D

__device__ __forceinline__ float bf2f(u16 h) {
    union { u32 u; float f; } v; v.u = (u32)h << 16; return v.f;
}
__device__ __forceinline__ u16 f2bf_bits(float f) {
    u32 u = __float_as_uint(f);
    u32 r = (u + 0x7fffu + ((u >> 16) & 1u)) >> 16;   // RNE
    return (u16)r;
}
__device__ __forceinline__ u32 pack2(float a, float b) {
    return (u32)f2bf_bits(a) | ((u32)f2bf_bits(b) << 16);
}

// ---------------------------------------------------------------------------
// fp32 -> bf16 weight convert. n4 = count/4.
// ---------------------------------------------------------------------------
__global__ __launch_bounds__(256) void f2bf_kernel(
    const float* __restrict__ src, u16* __restrict__ dst, int n4)
{
    int i = blockIdx.x * 256 + threadIdx.x;
    if (i < n4) {
        float4 v = ((const float4*)src)[i];
        uint2 p; p.x = pack2(v.x, v.y); p.y = pack2(v.z, v.w);
        ((uint2*)dst)[i] = p;
    }
}

// ---------------------------------------------------------------------------
// LayerNorm over C + transpose: x fp32 [b][c][n] -> outT bf16 [b][n][c].
// Thread per (b,n); strided reads coalesced across threads; 512B row writes.
// grid 256, block 256.
// ---------------------------------------------------------------------------
__global__ __launch_bounds__(256) void ln_t_f32(
    const float* __restrict__ x, const float* __restrict__ wgt,
    const float* __restrict__ bias, u16* __restrict__ outT)
{
    __shared__ float sw[CCH], sb[CCH];
    int tid = threadIdx.x;
    sw[tid] = wgt[tid]; sb[tid] = bias[tid];
    __syncthreads();
    int pos = blockIdx.x * 256 + tid;
    int b = pos >> 12, n = pos & 4095;
    const float* xp = x + (size_t)b * CCH * HWP + n;
    float s = 0.f, ss = 0.f;
    #pragma unroll 8
    for (int c = 0; c < CCH; ++c) { float v = xp[(size_t)c * HWP]; s += v; ss += v * v; }
    float u = s * (1.0f / CCH);
    float r = rsqrtf(ss * (1.0f / CCH) - u * u + 1e-6f);
    u16* op = outT + ((size_t)b * HWP + n) * CCH;
    for (int c0 = 0; c0 < CCH; c0 += 8) {
        u16 tmp[8];
        #pragma unroll
        for (int j = 0; j < 8; ++j) {
            float v = xp[(size_t)(c0 + j) * HWP];
            tmp[j] = f2bf_bits(sw[c0 + j] * (v - u) * r + sb[c0 + j]);
        }
        *(uint4*)(op + c0) = *(uint4*)tmp;
    }
}

// Same, but input already bf16 T-layout [b][n][c] (used for LN of x).
__global__ __launch_bounds__(256) void ln_t_bf16T(
    const u16* __restrict__ xT, const float* __restrict__ wgt,
    const float* __restrict__ bias, u16* __restrict__ outT)
{
    __shared__ float sw[CCH], sb[CCH];
    int tid = threadIdx.x;
    sw[tid] = wgt[tid]; sb[tid] = bias[tid];
    __syncthreads();
    int pos = blockIdx.x * 256 + tid;
    int b = pos >> 12, n = pos & 4095;
    const u16* xp = xT + ((size_t)b * HWP + n) * CCH;
    float s = 0.f, ss = 0.f;
    for (int c0 = 0; c0 < CCH; c0 += 8) {
        uint4 w4 = *(const uint4*)(xp + c0);
        const u16* ph = (const u16*)&w4;
        #pragma unroll
        for (int j = 0; j < 8; ++j) { float v = bf2f(ph[j]); s += v; ss += v * v; }
    }
    float u = s * (1.0f / CCH);
    float r = rsqrtf(ss * (1.0f / CCH) - u * u + 1e-6f);
    u16* op = outT + ((size_t)b * HWP + n) * CCH;
    for (int c0 = 0; c0 < CCH; c0 += 8) {
        uint4 w4 = *(const uint4*)(xp + c0);
        const u16* ph = (const u16*)&w4;
        u16 tmp[8];
        #pragma unroll
        for (int j = 0; j < 8; ++j)
            tmp[j] = f2bf_bits(sw[c0 + j] * (bf2f(ph[j]) - u) * r + sb[c0 + j]);
        *(uint4*)(op + c0) = *(uint4*)tmp;
    }
}

// ---------------------------------------------------------------------------
// MFMA GEMM: Out[b][m][n] = sum_k Wb[m][k] * XT[b][n][k]   (K=256)
// 128x128 block tile, 4 waves (2x2), each wave 64x64 = 4x4 MFMA 16x16x32.
// MODE 0: orig bf16 out                      (q, fc1)
// MODE 1: m<256 -> orig bf16 K; m>=256 -> T bf16 V        (kv)
// MODE 2: +bias +resF(img); fp32 orig outF (d_out) AND T bf16 outB (xT)
// MODE 3: +resF; fp32 orig outF (d_out)     (fc2)
// grid: (32, M/128, 16)
// ---------------------------------------------------------------------------
template<int MODE>
__global__ __launch_bounds__(256) void gemmT(
    const u16* __restrict__ Wb, const u16* __restrict__ XT,
    u16* __restrict__ outA, u16* __restrict__ outB,
    float* __restrict__ outF, const float* __restrict__ bias,
    const float* __restrict__ resF)
{
    int tid = threadIdx.x;
    int w = tid >> 6, lane = tid & 63;
    int lr = lane & 15, quad = lane >> 4;
    int wm = w >> 1, wn = w & 1;
    int b  = blockIdx.z;
    int m0 = blockIdx.y * 128 + wm * 64;
    int n0 = blockIdx.x * 128 + wn * 64;

    f32x4 zz = {0.f, 0.f, 0.f, 0.f};
    f32x4 acc[4][4];
    #pragma unroll
    for (int i = 0; i < 4; ++i)
        #pragma unroll
        for (int j = 0; j < 4; ++j) acc[i][j] = zz;

    const u16* Ab = Wb + (size_t)(m0 + lr) * CCH + quad * 8;
    const u16* Bb = XT + ((size_t)b * HWP + n0 + lr) * CCH + quad * 8;

    #pragma unroll
    for (int k0 = 0; k0 < 256; k0 += 32) {
        bf16x8 a[4], bb[4];
        #pragma unroll
        for (int mi = 0; mi < 4; ++mi) a[mi]  = *(const bf16x8*)(Ab + (size_t)mi * 16 * CCH + k0);
        #pragma unroll
        for (int nj = 0; nj < 4; ++nj) bb[nj] = *(const bf16x8*)(Bb + (size_t)nj * 16 * CCH + k0);
        #pragma unroll
        for (int mi = 0; mi < 4; ++mi)
            #pragma unroll
            for (int nj = 0; nj < 4; ++nj)
                acc[mi][nj] = __builtin_amdgcn_mfma_f32_16x16x32_bf16(a[mi], bb[nj], acc[mi][nj], 0, 0, 0);
    }

    #pragma unroll
    for (int mi = 0; mi < 4; ++mi) {
        int mbase = m0 + mi * 16 + quad * 4;   // 4 consecutive m via reg idx
        #pragma unroll
        for (int nj = 0; nj < 4; ++nj) {
            int n = n0 + nj * 16 + lr;
            if (MODE == 0 || (MODE == 1 && m0 < 256)) {
                size_t base = ((size_t)b * CCH + mbase) * HWP + n;
                #pragma unroll
                for (int r = 0; r < 4; ++r)
                    outA[base + (size_t)r * HWP] = f2bf_bits(acc[mi][nj][r]);
            } else if (MODE == 1) {            // V-half -> T layout
                uint2 p;
                p.x = pack2(acc[mi][nj][0], acc[mi][nj][1]);
                p.y = pack2(acc[mi][nj][2], acc[mi][nj][3]);
                *(uint2*)(outB + ((size_t)b * HWP + n) * CCH + (mbase - 256)) = p;
            } else if (MODE == 2) {
                float v[4];
                size_t rb = ((size_t)b * CCH + mbase) * HWP + n;
                #pragma unroll
                for (int r = 0; r < 4; ++r) {
                    v[r] = acc[mi][nj][r] + bias[mbase + r] + resF[rb + (size_t)r * HWP];
                    outF[rb + (size_t)r * HWP] = v[r];
                }
                uint2 p; p.x = pack2(v[0], v[1]); p.y = pack2(v[2], v[3]);
                *(uint2*)(outB + ((size_t)b * HWP + n) * CCH + mbase) = p;
            } else {                           // MODE 3
                size_t rb = ((size_t)b * CCH + mbase) * HWP + n;
                #pragma unroll
                for (int r = 0; r < 4; ++r)
                    outF[rb + (size_t)r * HWP] = acc[mi][nj][r] + resF[rb + (size_t)r * HWP];
            }
        }
    }
}

// ---------------------------------------------------------------------------
// Reciprocal L2 row norms over HW (vectorized uint4 loads).
// grid: 3*B*C blocks, block 256.
// ---------------------------------------------------------------------------
__global__ __launch_bounds__(256) void rownorm_kernel(
    const u16* __restrict__ q, const u16* __restrict__ Ktex, const u16* __restrict__ Kdep,
    float* __restrict__ rq, float* __restrict__ rkt, float* __restrict__ rkd)
{
    int tid = threadIdx.x;
    int idx = blockIdx.x;
    int which = idx >> 12;
    int bc = idx & 4095;
    const u16* row = (which == 0 ? q : which == 1 ? Ktex : Kdep) + (size_t)bc * HWP;
    float* out = (which == 0 ? rq : which == 1 ? rkt : rkd) + bc;
    float s = 0.f;
    const uint4* r4 = (const uint4*)row;
    #pragma unroll
    for (int it = 0; it < 2; ++it) {
        uint4 v = r4[tid * 2 + it];
        const u16* ph = (const u16*)&v;
        #pragma unroll
        for (int j = 0; j < 8; ++j) { float f = bf2f(ph[j]); s += f * f; }
    }
    #pragma unroll
    for (int off = 32; off > 0; off >>= 1) s += __shfl_down(s, off, 64);
    __shared__ float red[4];
    if ((tid & 63) == 0) red[tid >> 6] = s;
    __syncthreads();
    if (tid == 0) {
        float t = red[0] + red[1] + red[2] + red[3];
        out[0] = 1.0f / fmaxf(sqrtf(t), 1e-12f);
    }
}

// ---------------------------------------------------------------------------
// Scores partial (MFMA): Sp[which][bh][nc][c][d] = sum_{n in chunk} q[c][n]k[d][n]
// grid (8 nchunk, 64 bh, 2 which), block 256.
// ---------------------------------------------------------------------------
__global__ __launch_bounds__(256) void scores_mfma(
    const u16* __restrict__ q, const u16* __restrict__ Ktex, const u16* __restrict__ Kdep,
    float* __restrict__ Sp)
{
    int tid = threadIdx.x;
    int w = tid >> 6, lane = tid & 63;
    int lr = lane & 15, quad = lane >> 4;
    int nc = blockIdx.x, bh = blockIdx.y, which = blockIdx.z;
    int b = bh >> 2, h = bh & 3;
    const u16* Q = q + ((size_t)b * CCH + h * 64) * HWP;
    const u16* K = (which ? Kdep : Ktex) + ((size_t)b * CCH + h * 64) * HWP;

    f32x4 zz = {0.f, 0.f, 0.f, 0.f};
    f32x4 acc[4] = {zz, zz, zz, zz};
    const u16* Ab = Q + (size_t)(w * 16 + lr) * HWP + nc * 512 + quad * 8;
    const u16* Bb = K + (size_t)lr * HWP + nc * 512 + quad * 8;

    #pragma unroll 4
    for (int s = 0; s < 16; ++s) {
        int off = s * 32;
        bf16x8 a = *(const bf16x8*)(Ab + off);
        #pragma unroll
        for (int dj = 0; dj < 4; ++dj) {
            bf16x8 kb = *(const bf16x8*)(Bb + (size_t)dj * 16 * HWP + off);
            acc[dj] = __builtin_amdgcn_mfma_f32_16x16x32_bf16(a, kb, acc[dj], 0, 0, 0);
        }
    }
    float* out = Sp + (((size_t)(which * 64 + bh) * 8 + nc) * 4096);
    #pragma unroll
    for (int dj = 0; dj < 4; ++dj)
        #pragma unroll
        for (int r = 0; r < 4; ++r)
            out[(w * 16 + quad * 4 + r) * 64 + dj * 16 + lr] = acc[dj][r];
}

// ---------------------------------------------------------------------------
// Reduce partials + scale (rq*rk) + softmax + gate fold -> P bf16 [2][bh][c][d]
// grid (64 bh, 2 which), block 256.
// ---------------------------------------------------------------------------
__global__ __launch_bounds__(256) void softmax_kernel(
    const float* __restrict__ Sp, const float* __restrict__ rq,
    const float* __restrict__ rkt, const float* __restrict__ rkd,
    const float* __restrict__ ascale, u16* __restrict__ Pp)
{
    __shared__ float S[64][65];
    int tid = threadIdx.x;
    int bh = blockIdx.x, which = blockIdx.y;
    int b = bh >> 2, h = bh & 3;
    float g = 1.0f / (1.0f + expf(-ascale[h]));
    float gain = which ? (1.0f - g) : g;
    const float* base = Sp + ((size_t)(which * 64 + bh) * 8) * 4096;
    const float* rk  = (which ? rkd : rkt) + b * CCH + h * 64;
    const float* rqp = rq + b * CCH + h * 64;
    for (int i = tid; i < 4096; i += 256) {
        float s = 0.f;
        #pragma unroll
        for (int p = 0; p < 8; ++p) s += base[(size_t)p * 4096 + i];
        S[i >> 6][i & 63] = s * rqp[i >> 6] * rk[i & 63];
    }
    __syncthreads();
    if (tid < 64) {
        float mx = -1e30f;
        #pragma unroll 8
        for (int d = 0; d < 64; ++d) mx = fmaxf(mx, S[tid][d]);
        float sum = 0.f;
        #pragma unroll 8
        for (int d = 0; d < 64; ++d) { float e = expf(S[tid][d] - mx); S[tid][d] = e; sum += e; }
        float inv = gain / sum;
        u16* dst = Pp + ((size_t)(which * 64 + bh) * 64 + tid) * 64;
        #pragma unroll 8
        for (int d = 0; d < 64; ++d) dst[d] = f2bf_bits(S[tid][d] * inv);
    }
}

// ---------------------------------------------------------------------------
// PV (MFMA): qkvT[b][n][h*64+c] = sum_d P[c][d]*VT[n][d] over both sources.
// grid (16 nchunk, 64 bh), block 256.
// ---------------------------------------------------------------------------
__global__ __launch_bounds__(256) void pv_mfma(
    const u16* __restrict__ Pp, const u16* __restrict__ VtexT,
    const u16* __restrict__ VdepT, u16* __restrict__ qkvT)
{
    int tid = threadIdx.x;
    int w = tid >> 6, lane = tid & 63;
    int lr = lane & 15, quad = lane >> 4;
    int nc = blockIdx.x, bh = blockIdx.y;
    int b = bh >> 2, h = bh & 3;
    int n0 = nc * 256 + w * 64;

    f32x4 zz = {0.f, 0.f, 0.f, 0.f};
    f32x4 acc[4][4];
    #pragma unroll
    for (int i = 0; i < 4; ++i)
        #pragma unroll
        for (int j = 0; j < 4; ++j) acc[i][j] = zz;

    #pragma unroll
    for (int src = 0; src < 2; ++src) {
        const u16* P  = Pp + ((size_t)(src * 64 + bh) * 64) * 64;
        const u16* VT = (src ? VdepT : VtexT);
        const u16* Vb = VT + ((size_t)b * HWP + n0 + lr) * CCH + h * 64 + quad * 8;
        #pragma unroll
        for (int ks = 0; ks < 2; ++ks) {
            bf16x8 a[4], vv[4];
            #pragma unroll
            for (int ci = 0; ci < 4; ++ci)
                a[ci] = *(const bf16x8*)(P + (size_t)(ci * 16 + lr) * 64 + ks * 32 + quad * 8);
            #pragma unroll
            for (int nj = 0; nj < 4; ++nj)
                vv[nj] = *(const bf16x8*)(Vb + (size_t)nj * 16 * CCH + ks * 32);
            #pragma unroll
            for (int ci = 0; ci < 4; ++ci)
                #pragma unroll
                for (int nj = 0; nj < 4; ++nj)
                    acc[ci][nj] = __builtin_amdgcn_mfma_f32_16x16x32_bf16(a[ci], vv[nj], acc[ci][nj], 0, 0, 0);
        }
    }
    #pragma unroll
    for (int ci = 0; ci < 4; ++ci)
        #pragma unroll
        for (int nj = 0; nj < 4; ++nj) {
            int n = n0 + nj * 16 + lr;
            uint2 p;
            p.x = pack2(acc[ci][nj][0], acc[ci][nj][1]);
            p.y = pack2(acc[ci][nj][2], acc[ci][nj][3]);
            *(uint2*)(qkvT + ((size_t)b * HWP + n) * CCH + h * 64 + ci * 16 + quad * 4) = p;
        }
}

// ---------------------------------------------------------------------------
// Depthwise 3x3 + exact GELU, LDS-staged.
// Block = (8-ch group cg, half-plane nh, batch b). LDS: 8 planes of 34 rows
// (incl. zero-filled halo) x 64 cols, row stride 72 u16 (16B aligned).
// Each thread: 8 consecutive n x 8 ch; one ds_read_b128 per (ch,row);
// one 16B global store per n (8 channels packed).
// grid (32, 2, 16), block 256.
// ---------------------------------------------------------------------------
__global__ __launch_bounds__(256) void dwgelu_plane(
    const u16* __restrict__ y1, const float* __restrict__ dww, u16* __restrict__ y2T)
{
    __shared__ u16 plane[8 * 34 * 72];   // 39168 B
    __shared__ float sdw[72];
    int tid = threadIdx.x;
    int cg = blockIdx.x, nh = blockIdx.y, b = blockIdx.z;
    if (tid < 72) sdw[tid] = dww[cg * 72 + tid];

    // fill: 8 ch x 34 rows x 8 uint4-chunks = 2176 chunks
    for (int idx = tid; idx < 2176; idx += 256) {
        int cl  = idx / 272;
        int rem = idx - cl * 272;
        int r   = rem >> 3;
        int cc  = (rem & 7) << 3;
        int gr  = nh * 32 + r - 1;
        uint4 v = make_uint4(0u, 0u, 0u, 0u);
        if ((unsigned)gr < 64u)
            v = *(const uint4*)(y1 + ((size_t)b * CCH + cg * 8 + cl) * HWP + gr * 64 + cc);
        *(uint4*)&plane[cl * 2448 + r * 72 + cc] = v;
    }
    __syncthreads();

    int nb  = tid * 8;           // 0..2047 within half-plane
    int lrow = nb >> 6;          // 0..31
    int ww0  = nb & 63;          // multiple of 8
    float acc[8][8];
    #pragma unroll
    for (int i = 0; i < 8; ++i)
        #pragma unroll
        for (int c = 0; c < 8; ++c) acc[i][c] = 0.f;

    #pragma unroll
    for (int cl = 0; cl < 8; ++cl) {
        const u16* pl = &plane[cl * 2448];
        #pragma unroll
        for (int dy = 0; dy < 3; ++dy) {
            int pr = lrow + dy;              // plane row (halo handles borders)
            const u16* rowp = pl + pr * 72 + ww0;
            uint4 m = *(const uint4*)rowp;
            const u16* mh = (const u16*)&m;
            float s[10];
            #pragma unroll
            for (int j = 0; j < 8; ++j) s[j + 1] = bf2f(mh[j]);
            s[0] = (ww0 > 0)  ? bf2f(rowp[-1]) : 0.f;
            s[9] = (ww0 < 56) ? bf2f(rowp[8])  : 0.f;
            float w0 = sdw[cl * 9 + dy * 3 + 0];
            float w1 = sdw[cl * 9 + dy * 3 + 1];
            float w2 = sdw[cl * 9 + dy * 3 + 2];
            #pragma unroll
            for (int i = 0; i < 8; ++i)
                acc[i][cl] += s[i] * w0 + s[i + 1] * w1 + s[i + 2] * w2;
        }
    }

    size_t outbase = ((size_t)b * HWP + nh * 2048 + nb) * CCH + cg * 8;
    #pragma unroll
    for (int i = 0; i < 8; ++i) {
        u16 tmp[8];
        #pragma unroll
        for (int c = 0; c < 8; ++c) {
            float a = acc[i][c];
            tmp[c] = f2bf_bits(0.5f * a * (1.0f + erff(a * 0.70710678118654752f)));
        }
        *(uint4*)(y2T + outbase + (size_t)i * CCH) = *(uint4*)tmp;
    }
}

// ---------------------------------------------------------------------------
// Workspace (~210 MB): lnT 32 | q 32 | Ktex 32 | VtexT 32 | Kdep 32 | VdepT 32
//   | Sp 16 | Pp 1 | norms 48K | wbf 784K.  Aliases: qkvT=lnT; xT=qbuf;
//   y1=Ktex; y2T=VtexT.  x lives in d_out (fp32).
// ---------------------------------------------------------------------------
extern "C" void kernel_launch(void* const* d_in, const int* in_sizes, int n_in,
                              void* d_out, int out_size, void* d_ws, size_t ws_size,
                              hipStream_t stream)
{
    const float* img    = (const float*)d_in[0];
    const float* tex    = (const float*)d_in[1];
    const float* dep    = (const float*)d_in[2];
    const float* qnw    = (const float*)d_in[3];
    const float* qnb    = (const float*)d_in[4];
    const float* kvnw   = (const float*)d_in[5];
    const float* kvnb   = (const float*)d_in[6];
    const float* ascale = (const float*)d_in[7];
    const float* qpw    = (const float*)d_in[8];
    const float* kvpw   = (const float*)d_in[9];
    const float* opw    = (const float*)d_in[10];
    const float* opb    = (const float*)d_in[11];
    const float* fnw    = (const float*)d_in[12];
    const float* fnb    = (const float*)d_in[13];
    const float* fc1w   = (const float*)d_in[14];
    const float* dww    = (const float*)d_in[15];
    const float* fc2w   = (const float*)d_in[16];
    float* out = (float*)d_out;

    const size_t TEN = (size_t)BQ * CCH * HWP;   // 16,777,216
    char* p = (char*)d_ws;
    u16* lnT   = (u16*)p; p += TEN * 2;
    u16* qbuf  = (u16*)p; p += TEN * 2;
    u16* Ktex  = (u16*)p; p += TEN * 2;
    u16* VtexT = (u16*)p; p += TEN * 2;
    u16* Kdep  = (u16*)p; p += TEN * 2;
    u16* VdepT = (u16*)p; p += TEN * 2;
    float* Sp  = (float*)p; p += (size_t)8 * 2 * 64 * 4096 * 4;   // 16 MB
    u16* Pp    = (u16*)p;  p += (size_t)2 * 64 * 64 * 64 * 2;     // 1 MB
    float* rq  = (float*)p; p += (size_t)BQ * CCH * 4;
    float* rkt = (float*)p; p += (size_t)BQ * CCH * 4;
    float* rkd = (float*)p; p += (size_t)BQ * CCH * 4;
    u16* wq  = (u16*)p; p += 65536 * 2;
    u16* wkv = (u16*)p; p += 131072 * 2;
    u16* wo  = (u16*)p; p += 65536 * 2;
    u16* wf1 = (u16*)p; p += 65536 * 2;
    u16* wf2 = (u16*)p; p += 65536 * 2;
    u16* qkvT = lnT;     // alias
    u16* xT   = qbuf;    // alias
    u16* y1   = Ktex;    // alias
    u16* y2T  = VtexT;   // alias

    dim3 blk(256);
    // weight converts
    f2bf_kernel<<<64,  blk, 0, stream>>>(qpw,  wq,  16384);
    f2bf_kernel<<<128, blk, 0, stream>>>(kvpw, wkv, 32768);
    f2bf_kernel<<<64,  blk, 0, stream>>>(opw,  wo,  16384);
    f2bf_kernel<<<64,  blk, 0, stream>>>(fc1w, wf1, 16384);
    f2bf_kernel<<<64,  blk, 0, stream>>>(fc2w, wf2, 16384);
    // projections
    ln_t_f32<<<256, blk, 0, stream>>>(img, qnw, qnb, lnT);
    gemmT<0><<<dim3(32, 2, 16), blk, 0, stream>>>(wq, lnT, qbuf, (u16*)0, (float*)0, (const float*)0, (const float*)0);
    ln_t_f32<<<256, blk, 0, stream>>>(tex, kvnw, kvnb, lnT);
    gemmT<1><<<dim3(32, 4, 16), blk, 0, stream>>>(wkv, lnT, Ktex, VtexT, (float*)0, (const float*)0, (const float*)0);
    ln_t_f32<<<256, blk, 0, stream>>>(dep, kvnw, kvnb, lnT);
    gemmT<1><<<dim3(32, 4, 16), blk, 0, stream>>>(wkv, lnT, Kdep, VdepT, (float*)0, (const float*)0, (const float*)0);
    // attention
    rownorm_kernel<<<3 * 4096, blk, 0, stream>>>(qbuf, Ktex, Kdep, rq, rkt, rkd);
    scores_mfma<<<dim3(8, 64, 2), blk, 0, stream>>>(qbuf, Ktex, Kdep, Sp);
    softmax_kernel<<<dim3(64, 2), blk, 0, stream>>>(Sp, rq, rkt, rkd, ascale, Pp);
    pv_mfma<<<dim3(16, 64), blk, 0, stream>>>(Pp, VtexT, VdepT, qkvT);
    // x = img + o_proj(qkv) + b  (fp32 in d_out, bf16 xT in ws)
    gemmT<2><<<dim3(32, 2, 16), blk, 0, stream>>>(wo, qkvT, (u16*)0, xT, out, opb, img);
    // FFN
    ln_t_bf16T<<<256, blk, 0, stream>>>(xT, fnw, fnb, lnT);
    gemmT<0><<<dim3(32, 2, 16), blk, 0, stream>>>(wf1, lnT, y1, (u16*)0, (float*)0, (const float*)0, (const float*)0);
    dwgelu_plane<<<dim3(32, 2, 16), blk, 0, stream>>>(y1, dww, y2T);
    gemmT<3><<<dim3(32, 2, 16), blk, 0, stream>>>(wf2, y2T, (u16*)0, (u16*)0, out, (const float*)0, out);
}